// Round 1
// baseline (724.097 us; speedup 1.0000x reference)
//
#include <hip/hip_runtime.h>
#include <stdint.h>
#include <math.h>

constexpr int S_LEN = 128;
constexpr int F_DIM = 256;
constexpr int F4    = F_DIM / 4;
constexpr int ROWS  = 16;   // rows of x per mlp block

// ---------------------------------------------------------------------------
// Kernel 1: masked sum pooling.  grid = B/4 blocks x 256 threads.
// Wave w handles batch row b = blockIdx*4 + w; lane l holds float4 at f=4l.
// Memory-bound: 512 MiB streaming read of token_embeds, coalesced 16 B/lane.
// Mask dtype (bool) representation is detected at runtime from the first
// 64 u32 words: float32 (0x3F800000 pattern) / uint8 bytes / int32.
// ---------------------------------------------------------------------------
__global__ __launch_bounds__(256) void pool_kernel(
    const float* __restrict__ te, const void* __restrict__ mask,
    float* __restrict__ xout)
{
  const int t    = threadIdx.x;
  const int wave = t >> 6;
  const int lane = t & 63;
  const long b   = (long)blockIdx.x * 4 + wave;

  // --- mask format detection (wave-uniform, same result in every block) ---
  const uint32_t* mw = (const uint32_t*)mask;
  uint32_t v = mw[lane];                       // first 256 bytes, L2-hot
  unsigned long long isF  = __ballot(v == 0x3F800000u);
  unsigned long long big  = __ballot(v > 1u);
  const int fmt = isF ? 2 : (big ? 1 : 0);     // 0=int32, 1=uint8, 2=float32

  const float4* te4  = (const float4*)te;
  const long    tb   = b * S_LEN * F4 + lane;  // float4 index of (b, s=0, 4*lane)
  const long    mb   = b * S_LEN;

  float4 acc = make_float4(0.f, 0.f, 0.f, 0.f);

  if (fmt == 0) {
    const int* mi = (const int*)mask;
    #pragma unroll 4
    for (int s = 0; s < S_LEN; ++s) {
      float  m  = (float)mi[mb + s];
      float4 tv = te4[tb + (long)s * F4];
      acc.x = fmaf(m, tv.x, acc.x); acc.y = fmaf(m, tv.y, acc.y);
      acc.z = fmaf(m, tv.z, acc.z); acc.w = fmaf(m, tv.w, acc.w);
    }
  } else if (fmt == 1) {
    const uint8_t* mu = (const uint8_t*)mask;
    #pragma unroll 4
    for (int s = 0; s < S_LEN; ++s) {
      float  m  = (float)mu[mb + s];
      float4 tv = te4[tb + (long)s * F4];
      acc.x = fmaf(m, tv.x, acc.x); acc.y = fmaf(m, tv.y, acc.y);
      acc.z = fmaf(m, tv.z, acc.z); acc.w = fmaf(m, tv.w, acc.w);
    }
  } else {
    const float* mf = (const float*)mask;
    #pragma unroll 4
    for (int s = 0; s < S_LEN; ++s) {
      float  m  = mf[mb + s];
      float4 tv = te4[tb + (long)s * F4];
      acc.x = fmaf(m, tv.x, acc.x); acc.y = fmaf(m, tv.y, acc.y);
      acc.z = fmaf(m, tv.z, acc.z); acc.w = fmaf(m, tv.w, acc.w);
    }
  }

  ((float4*)xout)[b * F4 + lane] = acc;
}

// ---------------------------------------------------------------------------
// Kernel 2: fused  x = tanh(x@W1^T + b1); x = tanh(x@W2^T + b2), in-place.
// grid = B/ROWS blocks x 256 threads (4 waves). Block stages its 16 x-rows
// into LDS, then for each layer streams W in 64-wide f-chunks, transposing
// into LDS during staging so the inner loop reads W^T columns as ds_read_b128
// (conflict-free consecutive layout) with broadcast x reads.
// In-place is safe: block reads only its own rows (staged to LDS) before
// overwriting them.
// ---------------------------------------------------------------------------
__global__ __launch_bounds__(256) void mlp_kernel(
    float* __restrict__ x,
    const float* __restrict__ W1, const float* __restrict__ b1,
    const float* __restrict__ W2, const float* __restrict__ b2)
{
  __shared__ float xs[ROWS][F_DIM];   // 16 KB: x rows, then y1 rows
  __shared__ float wt[64][F_DIM];     // 64 KB: transposed W chunk [f][j]

  const int t    = threadIdx.x;
  const int wave = t >> 6;
  const int lane = t & 63;
  const long rowBase = (long)blockIdx.x * ROWS;
  float4* xg = (float4*)(x + rowBase * F_DIM);

  // stage x rows (ROWS*F/4 = 1024 float4, 4 per thread, coalesced)
  #pragma unroll
  for (int k = 0; k < (ROWS * F4) / 256; ++k)
    ((float4*)&xs[0][0])[t + 256 * k] = xg[t + 256 * k];
  __syncthreads();

  const int r0 = wave * (ROWS / 4);   // 4 rows per wave
  const int c  = lane * 4;            // 4 output cols per lane

  for (int layer = 0; layer < 2; ++layer) {
    const float* W    = layer ? W2 : W1;
    const float* bias = layer ? b2 : b1;

    float4 bv = ((const float4*)bias)[lane];
    float4 acc[ROWS / 4];
    #pragma unroll
    for (int r = 0; r < ROWS / 4; ++r) acc[r] = bv;

    for (int fc = 0; fc < F_DIM; fc += 64) {
      __syncthreads();  // protect wt from readers of previous chunk
      // stage W[j][fc..fc+63] -> wt[f-fc][j]; thread t owns row j=t.
      // Reads: 64 contiguous floats per row (coalesced). Writes: at each
      // step all threads hit consecutive addresses -> conflict-free.
      const float4* wrow = (const float4*)(W + (long)t * F_DIM + fc);
      #pragma unroll
      for (int k = 0; k < 16; ++k) {
        float4 wv = wrow[k];
        wt[4*k + 0][t] = wv.x; wt[4*k + 1][t] = wv.y;
        wt[4*k + 2][t] = wv.z; wt[4*k + 3][t] = wv.w;
      }
      __syncthreads();

      #pragma unroll 8
      for (int f = 0; f < 64; ++f) {
        float4 wv = *(const float4*)&wt[f][c];   // ds_read_b128, consecutive
        #pragma unroll
        for (int r = 0; r < ROWS / 4; ++r) {
          float xv = xs[r0 + r][fc + f];         // broadcast read
          acc[r].x = fmaf(xv, wv.x, acc[r].x);
          acc[r].y = fmaf(xv, wv.y, acc[r].y);
          acc[r].z = fmaf(xv, wv.z, acc[r].z);
          acc[r].w = fmaf(xv, wv.w, acc[r].w);
        }
      }
    }
    __syncthreads();
    // tanh epilogue -> xs (input of next layer / final result)
    #pragma unroll
    for (int r = 0; r < ROWS / 4; ++r) {
      float4 o;
      o.x = tanhf(acc[r].x); o.y = tanhf(acc[r].y);
      o.z = tanhf(acc[r].z); o.w = tanhf(acc[r].w);
      *(float4*)&xs[r0 + r][c] = o;
    }
    __syncthreads();
  }

  // write result rows back (coalesced)
  #pragma unroll
  for (int k = 0; k < (ROWS * F4) / 256; ++k)
    xg[t + 256 * k] = ((float4*)&xs[0][0])[t + 256 * k];
}

extern "C" void kernel_launch(void* const* d_in, const int* in_sizes, int n_in,
                              void* d_out, int out_size, void* d_ws, size_t ws_size,
                              hipStream_t stream) {
  const float* te   = (const float*)d_in[0];
  const void*  mask = d_in[1];
  const float* W1   = (const float*)d_in[2];
  const float* b1   = (const float*)d_in[3];
  const float* W2   = (const float*)d_in[4];
  const float* b2   = (const float*)d_in[5];
  float* out = (float*)d_out;

  const int Btot = in_sizes[0] / (S_LEN * F_DIM);   // 4096

  pool_kernel<<<dim3(Btot / 4), dim3(256), 0, stream>>>(te, mask, out);
  mlp_kernel<<<dim3(Btot / ROWS), dim3(256), 0, stream>>>(out, W1, b1, W2, b2);
}

// Round 2
// 671.637 us; speedup vs baseline: 1.0781x; 1.0781x over previous
//
#include <hip/hip_runtime.h>
#include <stdint.h>
#include <math.h>

constexpr int S_LEN = 128;
constexpr int F_DIM = 256;
constexpr int F4    = F_DIM / 4;
constexpr int ROWS  = 16;    // rows per mlp block

__device__ __forceinline__ int mbcnt64(unsigned long long m) {
  return __builtin_amdgcn_mbcnt_hi((unsigned)(m >> 32),
         __builtin_amdgcn_mbcnt_lo((unsigned)(m & 0xffffffffu), 0));
}
__device__ __forceinline__ void add4(float4& a, const float4 b) {
  a.x += b.x; a.y += b.y; a.z += b.z; a.w += b.w;
}
__device__ __forceinline__ void fma4(float4& a, float s, const float4 w) {
  a.x = fmaf(s, w.x, a.x); a.y = fmaf(s, w.y, a.y);
  a.z = fmaf(s, w.z, a.z); a.w = fmaf(s, w.w, a.w);
}

// ---------------------------------------------------------------------------
// Kernel 0: transpose W1,W2 (256x256 each) into d_ws: Wt[f][j] = W[j][f].
// Writes coalesced; reads are 1KiB-strided but the 256KB matrix is L2-hot.
// ---------------------------------------------------------------------------
__global__ __launch_bounds__(256) void wt_kernel(
    const float* __restrict__ W1, const float* __restrict__ W2,
    float* __restrict__ wsT)
{
  int id  = blockIdx.x * 256 + threadIdx.x;   // grid 512 -> 131072 threads
  int mat = id >> 16;
  int o   = id & 65535;
  int f   = o >> 8, j = o & 255;
  const float* W = mat ? W2 : W1;
  wsT[(mat << 16) + o] = W[j * 256 + f];
}

// ---------------------------------------------------------------------------
// Kernel 1: masked sum pooling with mask compaction.
// grid = B/4 blocks x 256 threads; wave w owns batch row b = blk*4+w.
// Mask is bool -> compact the active s-indices via ballot+mbcnt into LDS,
// then a dense 8-deep-unrolled loop of coalesced float4 loads (only masked
// rows are ever fetched: ~50% of te -> ~270MB HBM instead of 540MB).
// ---------------------------------------------------------------------------
__global__ __launch_bounds__(256) void pool_kernel(
    const float* __restrict__ te, const void* __restrict__ mask,
    float* __restrict__ xout)
{
  __shared__ int sl[4][132];

  const int t = threadIdx.x, w = t >> 6, l = t & 63;
  const long b = (long)blockIdx.x * 4 + w;

  // mask dtype detection (identical result in every wave/block)
  const uint32_t* mw = (const uint32_t*)mask;
  uint32_t v = mw[l];
  const int fmt = __ballot(v == 0x3F800000u) ? 2 : (__ballot(v > 1u) ? 1 : 0);

  bool a0, a1;
  if (fmt == 0) {
    const int* m = (const int*)mask + b * S_LEN;
    a0 = m[l] != 0; a1 = m[64 + l] != 0;
  } else if (fmt == 1) {
    const uint8_t* m = (const uint8_t*)mask + b * S_LEN;
    a0 = m[l] != 0; a1 = m[64 + l] != 0;
  } else {
    const float* m = (const float*)mask + b * S_LEN;
    a0 = m[l] != 0.f; a1 = m[64 + l] != 0.f;
  }
  unsigned long long b0 = __ballot(a0), b1 = __ballot(a1);
  const int c0 = __popcll(b0);
  const int cnt = c0 + __popcll(b1);
  if (a0) sl[w][mbcnt64(b0)]      = l;
  if (a1) sl[w][c0 + mbcnt64(b1)] = 64 + l;
  __syncthreads();

  const float4* src = (const float4*)te + b * (S_LEN * F4) + l;
  float4 acc = make_float4(0.f, 0.f, 0.f, 0.f);

  int i = 0;
  for (; i + 8 <= cnt; i += 8) {
    int s0 = sl[w][i+0], s1 = sl[w][i+1], s2 = sl[w][i+2], s3 = sl[w][i+3];
    int s4 = sl[w][i+4], s5 = sl[w][i+5], s6 = sl[w][i+6], s7 = sl[w][i+7];
    float4 t0 = src[s0*F4], t1 = src[s1*F4], t2 = src[s2*F4], t3 = src[s3*F4];
    float4 t4 = src[s4*F4], t5 = src[s5*F4], t6 = src[s6*F4], t7 = src[s7*F4];
    add4(t0, t1); add4(t2, t3); add4(t4, t5); add4(t6, t7);
    add4(t0, t2); add4(t4, t6); add4(t0, t4); add4(acc, t0);
  }
  for (; i < cnt; ++i) add4(acc, src[sl[w][i] * F4]);

  ((float4*)xout)[b * F4 + l] = acc;
}

// ---------------------------------------------------------------------------
// Kernel 2: fused x = tanh(x@W1^T+b1); x = tanh(x@W2^T+b2), in-place on d_out.
// grid = B/16 x 256 thr (4 waves). Reads W^T from d_ws: chunk staging is a
// flat contiguous 64KB memcpy (coalesced b128 loads, conflict-free b128 LDS
// writes). Inner loop: 1 aligned ds_read_b128 (W^T cols) + 4 broadcast reads
// (own-wave x rows) + 16 FMA -> VALU/LDS-balanced.
// ---------------------------------------------------------------------------
__global__ __launch_bounds__(256) void mlp_kernel(
    float* __restrict__ x, const float* __restrict__ wsT,
    const float* __restrict__ b1, const float* __restrict__ b2)
{
  __shared__ float xs[ROWS][F_DIM];   // 16 KB
  __shared__ float wt[64][F_DIM];     // 64 KB

  const int t = threadIdx.x, w = t >> 6, l = t & 63;
  const long rowBase = (long)blockIdx.x * ROWS;
  float4* xg = (float4*)(x + rowBase * F_DIM);

  #pragma unroll
  for (int k = 0; k < (ROWS * F4) / 256; ++k)
    ((float4*)xs)[t + 256 * k] = xg[t + 256 * k];
  __syncthreads();

  const int r0 = w * 4;     // 4 rows per wave (own-wave data thereafter)
  const int c  = l * 4;     // 4 output cols per lane

  for (int layer = 0; layer < 2; ++layer) {
    const float* Wt   = wsT + layer * 65536;
    const float* bias = layer ? b2 : b1;

    float4 bv = ((const float4*)bias)[l];
    float4 acc0 = bv, acc1 = bv, acc2 = bv, acc3 = bv;

    for (int fc = 0; fc < F_DIM; fc += 64) {
      __syncthreads();                       // protect wt from prev readers
      const float4* src = (const float4*)(Wt + fc * F_DIM);  // contiguous!
      #pragma unroll
      for (int k = 0; k < 16; ++k)
        ((float4*)wt)[t + 256 * k] = src[t + 256 * k];
      __syncthreads();

      #pragma unroll 8
      for (int f = 0; f < 64; ++f) {
        float4 wv = *(const float4*)&wt[f][c];   // aligned, conflict-free
        float x0 = xs[r0+0][fc+f], x1 = xs[r0+1][fc+f];
        float x2 = xs[r0+2][fc+f], x3 = xs[r0+3][fc+f];
        fma4(acc0, x0, wv); fma4(acc1, x1, wv);
        fma4(acc2, x2, wv); fma4(acc3, x3, wv);
      }
    }
    // tanh epilogue into own-wave xs rows (no cross-wave sharing)
    float4 o0, o1, o2, o3;
    o0.x=tanhf(acc0.x); o0.y=tanhf(acc0.y); o0.z=tanhf(acc0.z); o0.w=tanhf(acc0.w);
    o1.x=tanhf(acc1.x); o1.y=tanhf(acc1.y); o1.z=tanhf(acc1.z); o1.w=tanhf(acc1.w);
    o2.x=tanhf(acc2.x); o2.y=tanhf(acc2.y); o2.z=tanhf(acc2.z); o2.w=tanhf(acc2.w);
    o3.x=tanhf(acc3.x); o3.y=tanhf(acc3.y); o3.z=tanhf(acc3.z); o3.w=tanhf(acc3.w);
    __syncthreads();                 // wt re-stage fence for next layer
    *(float4*)&xs[r0+0][c] = o0; *(float4*)&xs[r0+1][c] = o1;
    *(float4*)&xs[r0+2][c] = o2; *(float4*)&xs[r0+3][c] = o3;
  }
  __syncthreads();
  #pragma unroll
  for (int k = 0; k < (ROWS * F4) / 256; ++k)
    xg[t + 256 * k] = ((float4*)xs)[t + 256 * k];
}

extern "C" void kernel_launch(void* const* d_in, const int* in_sizes, int n_in,
                              void* d_out, int out_size, void* d_ws, size_t ws_size,
                              hipStream_t stream) {
  const float* te   = (const float*)d_in[0];
  const void*  mask = d_in[1];
  const float* W1   = (const float*)d_in[2];
  const float* b1   = (const float*)d_in[3];
  const float* W2   = (const float*)d_in[4];
  const float* b2   = (const float*)d_in[5];
  float* out  = (float*)d_out;
  float* wsT  = (float*)d_ws;       // 512 KB: [Wt1 | Wt2]

  const int Btot = in_sizes[0] / (S_LEN * F_DIM);   // 4096

  wt_kernel  <<<dim3(512),        dim3(256), 0, stream>>>(W1, W2, wsT);
  pool_kernel<<<dim3(Btot / 4),   dim3(256), 0, stream>>>(te, mask, out);
  mlp_kernel <<<dim3(Btot / ROWS), dim3(256), 0, stream>>>(out, wsT, b1, b2);
}